// Round 6
// baseline (232.541 us; speedup 1.0000x reference)
//
#include <hip/hip_runtime.h>
#include <hip/hip_bf16.h>

typedef __attribute__((ext_vector_type(8))) short short8;
typedef __attribute__((ext_vector_type(4))) float f32x4;

#define B_N 1024
#define D_K 512
#define C_N 100000
#define SCALE_F 64.0f
#define MARGIN_F 0.35f
#define MAXL 64.0f   // global logit bound: |cos|*64 <= 64
#define BMT 256
#define BNT 256
#define KT 32
#define NTILN 391    // ceil(100000/256)
#define NWG 1564     // 4 * 391

__device__ __forceinline__ float dot4(float4 a, float4 b) {
    return a.x * b.x + a.y * b.y + a.z * b.z + a.w * b.w;
}

// round-to-nearest-even f32 -> bf16 bits
__device__ __forceinline__ ushort f2b(float f) {
    unsigned int u = __float_as_uint(f);
    u = (u + 0x7FFFu + ((u >> 16) & 1u)) >> 16;
    return (ushort)u;
}

// ---------------- kernel A: normalize x rows -> bf16 ----------------
__global__ void norm_x_kernel(const float* __restrict__ x,
                              ushort* __restrict__ xnb) {
    int row = blockIdx.x * 4 + (threadIdx.x >> 6);
    int l = threadIdx.x & 63;
    const float4* rp = (const float4*)(x + (size_t)row * D_K);
    float4 a = rp[l], b = rp[64 + l];
    float ssq = dot4(a, a) + dot4(b, b);
#pragma unroll
    for (int m = 1; m < 64; m <<= 1) ssq += __shfl_xor(ssq, m);
    float inv = 1.0f / fmaxf(sqrtf(ssq), 1e-12f);
    a.x *= inv; a.y *= inv; a.z *= inv; a.w *= inv;
    b.x *= inv; b.y *= inv; b.z *= inv; b.w *= inv;
    ushort4 ua; ua.x = f2b(a.x); ua.y = f2b(a.y); ua.z = f2b(a.z); ua.w = f2b(a.w);
    ushort4 ub; ub.x = f2b(b.x); ub.y = f2b(b.y); ub.z = f2b(b.z); ub.w = f2b(b.w);
    ushort4* obp = (ushort4*)(xnb + (size_t)row * D_K);
    obp[l] = ua; obp[64 + l] = ub;
}

// ---------------- kernel B: normalize id_agent rows -> bf16 ----------------
__global__ void norm_w_kernel(const float* __restrict__ w,
                              ushort* __restrict__ wb) {
    int row = blockIdx.x * 4 + (threadIdx.x >> 6);
    int l = threadIdx.x & 63;
    const float4* rp = (const float4*)(w + (size_t)row * D_K);
    float4 a = rp[l], b = rp[64 + l];
    float ssq = dot4(a, a) + dot4(b, b);
#pragma unroll
    for (int m = 1; m < 64; m <<= 1) ssq += __shfl_xor(ssq, m);
    float inv = 1.0f / fmaxf(sqrtf(ssq), 1e-12f);
    a.x *= inv; a.y *= inv; a.z *= inv; a.w *= inv;
    b.x *= inv; b.y *= inv; b.z *= inv; b.w *= inv;
    ushort4 ua; ua.x = f2b(a.x); ua.y = f2b(a.y); ua.z = f2b(a.z); ua.w = f2b(a.w);
    ushort4 ub; ub.x = f2b(b.x); ub.y = f2b(b.y); ub.z = f2b(b.z); ub.w = f2b(b.w);
    ushort4* obp = (ushort4*)(wb + (size_t)row * D_K);
    obp[l] = ua; obp[64 + l] = ub;
}

// ------------- kernel C: disc loss partial + exact target logit -------------
__global__ void disc_kernel(const float* __restrict__ x,
                            const int* __restrict__ target,
                            const float* __restrict__ ida,
                            const float* __restrict__ bmat,
                            float* __restrict__ sums,
                            float* __restrict__ tlogit) {
    int row = blockIdx.x * 4 + (threadIdx.x >> 6);
    int l = threadIdx.x & 63;
    long t = (long)target[row];
    const float4* xp = (const float4*)(x + (size_t)row * D_K);
    const float4* wp = (const float4*)(ida + (size_t)t * D_K);
    const float4* bp = (const float4*)(bmat + (size_t)t * D_K);
    float4 x0 = xp[l], x1 = xp[64 + l];
    float4 w0 = wp[l], w1 = wp[64 + l];
    float4 b0 = bp[l], b1 = bp[64 + l];
    float xssq = dot4(x0, x0) + dot4(x1, x1);
    float wssq = dot4(w0, w0) + dot4(w1, w1);
    float bssq = dot4(b0, b0) + dot4(b1, b1);
#pragma unroll
    for (int m = 1; m < 64; m <<= 1) {
        xssq += __shfl_xor(xssq, m);
        wssq += __shfl_xor(wssq, m);
        bssq += __shfl_xor(bssq, m);
    }
    float xinv = 1.0f / fmaxf(sqrtf(xssq), 1e-12f);
    float winv = 1.0f / fmaxf(sqrtf(wssq), 1e-12f);
    float btn = sqrtf(bssq);
    float cs = fminf(btn, 0.05f) / fmaxf(btn, 1e-12f);

    float xs[8] = {x0.x, x0.y, x0.z, x0.w, x1.x, x1.y, x1.z, x1.w};
    float wv[8] = {w0.x, w0.y, w0.z, w0.w, w1.x, w1.y, w1.z, w1.w};
    float bv[8] = {b0.x, b0.y, b0.z, b0.w, b1.x, b1.y, b1.z, b1.w};
    float rss = 0.0f, dt = 0.0f;
#pragma unroll
    for (int i = 0; i < 8; ++i) {
        float xn = xs[i] * xinv;
        float wn = wv[i] * winv;
        float d = xn - wn;
        float r = d - bv[i] * cs;
        rss += r * r;
        dt += xn * wn;
    }
#pragma unroll
    for (int m = 1; m < 64; m <<= 1) {
        rss += __shfl_xor(rss, m);
        dt += __shfl_xor(dt, m);
    }
    if (l == 0) {
        atomicAdd(&sums[0], sqrtf(rss));
        tlogit[row] = SCALE_F * dt;
    }
}

// ------------- kernel D: 256x256 bf16 MFMA GEMM, 4-buffer K-pipeline with
//               counted vmcnt (never 0 in main loop), fused fixed-max sumexp ---------
__global__ __launch_bounds__(512, 2) void gemm_lse_kernel(const ushort* __restrict__ A,
                                                          const ushort* __restrict__ W,
                                                          float* __restrict__ rowsum) {
    __shared__ ushort Asl[32768];   // 64 KB: 4 bufs x [256 rows][32 k], 16B-slot XOR swizzled
    __shared__ ushort Bsl[32768];   // 64 KB

    int tid = threadIdx.x;
    int wave = tid >> 6, l = tid & 63;
    int wm = wave >> 2, wn = wave & 3;       // 2 M-waves x 4 N-waves
    int cl = l & 15, hi = l >> 4;

    // XCD-bijective swizzle (nwg=1564: q=195, r=4), mt-minor so the 4 blocks
    // sharing a W-tile are id-consecutive within one XCD's chunk.
    int orig = blockIdx.x;
    int xcd = orig & 7, idx = orig >> 3;
    const int q = NWG >> 3, r = NWG & 7;
    int wgid = (xcd < r ? xcd * (q + 1) : r * (q + 1) + (xcd - r) * q) + idx;
    int nt = wgid >> 2, mt = wgid & 3;
    int m0 = mt * BMT, n0 = nt * BNT;

    // ---- staging lane constants (dest linear, source pre-swizzled: rule #21) ----
    int rloc = tid >> 2;                       // row 0..127 within a 128-row half
    int sswz = (tid & 3) ^ (rloc & 3);         // logical 16B slot for this lane
    const ushort* asrc0 = A + (size_t)(m0 + rloc) * D_K + sswz * 8;
    const ushort* asrc1 = A + (size_t)(m0 + 128 + rloc) * D_K + sswz * 8;
    int rb0 = n0 + rloc;       if (rb0 > C_N - 1) rb0 = C_N - 1;
    int rb1 = n0 + 128 + rloc; if (rb1 > C_N - 1) rb1 = C_N - 1;
    const ushort* bsrc0 = W + (size_t)rb0 * D_K + sswz * 8;
    const ushort* bsrc1 = W + (size_t)rb1 * D_K + sswz * 8;
    int dst0 = wave * 512;                     // ushort idx, j=0 half (rows 0-127)
    int dst1 = 4096 + wave * 512;              // j=1 half (rows 128-255)

    // ---- ds_read lane constants: row stride 32 ushort (64B), slot hi ^ (row&3) ----
    int frs = (hi ^ (l & 3)) * 8;              // swizzled slot, ushort units
    int abase = wm * 4096 + cl * 32 + frs;     // + half*2048 + mi*512
    int bbase = wn * 2048 + cl * 32 + frs;     // + ni*512

    f32x4 acc[8][4];
#pragma unroll
    for (int a = 0; a < 8; ++a)
#pragma unroll
        for (int n = 0; n < 4; ++n) acc[a][n] = (f32x4){0.f, 0.f, 0.f, 0.f};

#define STAGE_A(T) do { int bo_ = ((T) & 3) * 8192;                                          \
    __builtin_amdgcn_global_load_lds((const __attribute__((address_space(1))) void*)(asrc0 + (T) * KT), \
        (__attribute__((address_space(3))) void*)&Asl[bo_ + dst0], 16, 0, 0);                \
    __builtin_amdgcn_global_load_lds((const __attribute__((address_space(1))) void*)(asrc1 + (T) * KT), \
        (__attribute__((address_space(3))) void*)&Asl[bo_ + dst1], 16, 0, 0); } while (0)

#define STAGE_B(T) do { int bo_ = ((T) & 3) * 8192;                                          \
    __builtin_amdgcn_global_load_lds((const __attribute__((address_space(1))) void*)(bsrc0 + (T) * KT), \
        (__attribute__((address_space(3))) void*)&Bsl[bo_ + dst0], 16, 0, 0);                \
    __builtin_amdgcn_global_load_lds((const __attribute__((address_space(1))) void*)(bsrc1 + (T) * KT), \
        (__attribute__((address_space(3))) void*)&Bsl[bo_ + dst1], 16, 0, 0); } while (0)

#define KTILE(T, WAITSTR, STG) do {                                                          \
    asm volatile("s_waitcnt " WAITSTR ::: "memory");                                         \
    __builtin_amdgcn_s_barrier();                                                            \
    const ushort* Ab_ = &Asl[((T) & 3) * 8192];                                              \
    const ushort* Bb_ = &Bsl[((T) & 3) * 8192];                                              \
    if (STG) STAGE_A((T) + 3);                                                               \
    short8 bf[4], af[4];                                                                     \
    _Pragma("unroll") for (int ni = 0; ni < 4; ++ni)                                         \
        bf[ni] = *(const short8*)&Bb_[bbase + ni * 512];                                     \
    _Pragma("unroll") for (int mi = 0; mi < 4; ++mi)                                         \
        af[mi] = *(const short8*)&Ab_[abase + mi * 512];                                     \
    asm volatile("s_waitcnt lgkmcnt(0)" ::: "memory");                                       \
    __builtin_amdgcn_sched_barrier(0);                                                       \
    __builtin_amdgcn_s_setprio(1);                                                           \
    _Pragma("unroll") for (int mi = 0; mi < 4; ++mi)                                         \
        _Pragma("unroll") for (int ni = 0; ni < 4; ++ni)                                     \
            acc[mi][ni] = __builtin_amdgcn_mfma_f32_16x16x32_bf16(af[mi], bf[ni], acc[mi][ni], 0, 0, 0); \
    __builtin_amdgcn_s_setprio(0);                                                           \
    if (STG) STAGE_B((T) + 3);                                                               \
    _Pragma("unroll") for (int mi = 0; mi < 4; ++mi)                                         \
        af[mi] = *(const short8*)&Ab_[abase + 2048 + mi * 512];                               \
    asm volatile("s_waitcnt lgkmcnt(0)" ::: "memory");                                       \
    __builtin_amdgcn_sched_barrier(0);                                                       \
    __builtin_amdgcn_s_setprio(1);                                                           \
    _Pragma("unroll") for (int mi = 0; mi < 4; ++mi)                                         \
        _Pragma("unroll") for (int ni = 0; ni < 4; ++ni)                                     \
            acc[4 + mi][ni] = __builtin_amdgcn_mfma_f32_16x16x32_bf16(af[mi], bf[ni], acc[4 + mi][ni], 0, 0, 0); \
    __builtin_amdgcn_s_setprio(0);                                                           \
} while (0)

    // prologue: fill buffers 0,1,2 (12 per-wave loads in flight)
    STAGE_A(0); STAGE_B(0);
    STAGE_A(1); STAGE_B(1);
    STAGE_A(2); STAGE_B(2);

    // main loop: wait is always counted (8 = 4 newest half-tiles may stay in flight)
    for (int t = 0; t < 13; ++t) {
        KTILE(t, "vmcnt(8)", 1);
    }
    KTILE(13, "vmcnt(8)", 0);
    KTILE(14, "vmcnt(4)", 0);
    KTILE(15, "vmcnt(0)", 0);

    // ---- epilogue: per-row sum of exp(s - 64), fixed global max (s <= 64) ----
    __syncthreads();                       // all LDS reads done before aliasing
    float* rs = (float*)Asl;               // 4 KB alias over buf0 (dead)
#pragma unroll
    for (int a = 0; a < 8; ++a) {
#pragma unroll
        for (int j = 0; j < 4; ++j) {
            float se = 0.0f;
#pragma unroll
            for (int ni = 0; ni < 4; ++ni) {
                int cg = n0 + wn * 64 + ni * 16 + cl;
                if (cg < C_N) se += __expf(acc[a][ni][j] * SCALE_F - MAXL);
            }
#pragma unroll
            for (int xm = 1; xm < 16; xm <<= 1) se += __shfl_xor(se, xm);
            if (cl == 0) {
                int row = wm * 128 + (a >> 2) * 64 + (a & 3) * 16 + hi * 4 + j;
                rs[wn * 256 + row] = se;
            }
        }
    }
    __syncthreads();
    if (tid < 256) {
        float s = rs[tid] + rs[256 + tid] + rs[512 + tid] + rs[768 + tid];
        atomicAdd(&rowsum[m0 + tid], s);
    }
#undef KTILE
#undef STAGE_A
#undef STAGE_B
}

// ------------- kernel E: per-row lse from fixed-max sumexp -> nll -> sums[1] -------------
__global__ void rowfin_kernel(const float* __restrict__ rowsum,
                              const float* __restrict__ tlogit,
                              float* __restrict__ sums) {
    __shared__ float red[4];
    int tid = threadIdx.x;
    int row = blockIdx.x * 256 + tid;
    float lse = MAXL + logf(rowsum[row]);
    float st = tlogit[row];
    // replace exp(st) by exp(st - 64*margin) inside the lse
    float corr = __expf(st - lse) * (__expf(-SCALE_F * MARGIN_F) - 1.0f);
    float lse2 = lse + log1pf(corr);
    float nll = lse2 - (st - SCALE_F * MARGIN_F);
#pragma unroll
    for (int xm = 1; xm < 64; xm <<= 1) nll += __shfl_xor(nll, xm);
    if ((tid & 63) == 0) red[tid >> 6] = nll;
    __syncthreads();
    if (tid == 0) atomicAdd(&sums[1], red[0] + red[1] + red[2] + red[3]);
}

// ------------- kernel F: finalize scalar output -------------
__global__ void finalize_kernel(const float* __restrict__ sums, float* __restrict__ out) {
    float disc = sums[0] * (1.0f / B_N);
    float logp = sums[1] * (1.0f / B_N);
    float p = __expf(-logp);
    float om = 1.0f - p;
    out[0] = 0.4f * disc + om * om * logp;
}

extern "C" void kernel_launch(void* const* d_in, const int* in_sizes, int n_in,
                              void* d_out, int out_size, void* d_ws, size_t ws_size,
                              hipStream_t stream) {
    const float* x = (const float*)d_in[0];
    const int* target = (const int*)d_in[1];
    const float* ida = (const float*)d_in[2];
    const float* bmat = (const float*)d_in[3];
    float* out = (float*)d_out;

    char* ws = (char*)d_ws;
    size_t off = 0;
    float* rowsum = (float*)(ws + off);  off += (size_t)B_N * 4;         // 4 KB
    float* sums = (float*)(ws + off);    off += 256;
    ushort* xnb = (ushort*)(ws + off);   off += (size_t)B_N * D_K * 2;   // 1 MB
    ushort* wbf = (ushort*)(ws + off);   off += (size_t)C_N * D_K * 2;   // 102.4 MB
    float* tlogit = (float*)(ws + off);  off += (size_t)B_N * 4;

    // zero rowsum + sums (contiguous region) every call — deterministic
    hipMemsetAsync(rowsum, 0, (size_t)B_N * 4 + 256, stream);

    norm_x_kernel<<<B_N / 4, 256, 0, stream>>>(x, xnb);
    norm_w_kernel<<<C_N / 4, 256, 0, stream>>>(ida, wbf);
    disc_kernel<<<B_N / 4, 256, 0, stream>>>(x, target, ida, bmat, sums, tlogit);
    gemm_lse_kernel<<<NWG, 512, 0, stream>>>(xnb, wbf, rowsum);
    rowfin_kernel<<<B_N / 256, 256, 0, stream>>>(rowsum, tlogit, sums);
    finalize_kernel<<<1, 1, 0, stream>>>(sums, out);
}